// Round 5
// baseline (2468.250 us; speedup 1.0000x reference)
//
#include <hip/hip_runtime.h>
#include <stdint.h>

// ---------------------------------------------------------------------------
// DecoderRnn: 2-layer LSTM (B=32, H=512) over T=64 steps + vocab softmax (V=32000)
//   Round-6 change: FUSE vocab softmax into k_serial, pipelined 2 steps deep.
//   k_vocab + k_scale (~850us serialized after the recurrence) are deleted;
//   their work rides the recurrence's latency slack (VALU was 18.5%, all
//   pipes idle). Per step t, each WG (w<250 owns a fixed 128-col chunk of V):
//     - scale+store probs(t-2): rowsums final (all WGs' vocab(t-2) atomics
//       precede their step-(t-1) postc(cntB); we are past waitc(cntB,256t))
//     - vocab(t-1): A = H2u[t-1] bf16 (published step t-1, relaxed-agent u64
//       loads), B = Wu chunk (constant per WG -> L2-hot), 16x16x32 MFMA,
//       exp -> 16 regs held across one step; partial rowsums atomicAdd into
//       rs[t][slot=w&31][row] (32-slot distribution caps same-line serial).
//   Probs are written ONCE, normalized (no 524MB rescale round-trip).
//   All ordering piggybacks on the existing cntA/cntB counter barriers.
//   Epilogue: vocab(63) + scale(62),(63) with one extra cntA round.
//   k_serial GEMV core unchanged from round 5 (strided ks, reg-blocked,
//   weights in LDS, distributed counter barrier).
// ---------------------------------------------------------------------------

constexpr int kH = 512;
constexpr int kB = 32;
constexpr int kT = 64;
constexpr int kV = 32000;
constexpr int kG = 2048;   // 4*kH gates
constexpr int kNWG = 256;  // serial-kernel workgroups (1 per CU)
constexpr int kWS = 129;   // weight LDS row stride in f4 (516 floats = +16B pad)
constexpr int kNV = 250;   // WGs carrying a 128-col vocab chunk (250*128=32000)

typedef __attribute__((ext_vector_type(4))) float f4;
typedef __attribute__((ext_vector_type(8))) short short8;
typedef unsigned long long u64;

struct us4 { unsigned short x, y, z, w; };

__device__ inline unsigned short f2bf(float x) {
  union { float f; unsigned u; } c; c.f = x;
  unsigned r = c.u + 0x7fffu + ((c.u >> 16) & 1u);   // RNE to bf16
  return (unsigned short)(r >> 16);
}
__device__ inline float sigm(float x) { return 1.0f / (1.0f + expf(-x)); }

// ---------------------------------------------------------------------- K1
__global__ void k_init(float* __restrict__ buf2, float* __restrict__ rs,
                       int* __restrict__ flags /* 512 ints */) {
  int id = blockIdx.x * 256 + threadIdx.x;    // grid 64 -> 16384 threads
  f4 z = {0.f, 0.f, 0.f, 0.f};
  if (id < 8192) ((f4*)buf2)[id] = z;         // both h2 buffers = 0
  ((f4*)rs)[id] = z;                          // 16384 f4 = 64*1024 floats
  if (id < 512)  flags[id] = 0;
}

// ---------------------------------------------------------------------- K2
__global__ void k_wcvt(const float* __restrict__ W, unsigned short* __restrict__ Wu) {
  const int total = kV * kH / 4;
  for (int i = blockIdx.x * blockDim.x + threadIdx.x; i < total;
       i += gridDim.x * blockDim.x) {
    f4 v = ((const f4*)W)[i];
    us4 o = {f2bf(v.x), f2bf(v.y), f2bf(v.z), f2bf(v.w)};
    ((us4*)Wu)[i] = o;
  }
}

// ---------------------------------------------------------------------- K3
__global__ __launch_bounds__(256) void k_xg1(
    const int* __restrict__ inputs, const int* __restrict__ tseq,
    const float* __restrict__ emb, const float* __restrict__ Wih1,
    const float* __restrict__ bih1, const float* __restrict__ bhh1,
    float* __restrict__ Xg1T) {
  __shared__ float Xs[kB * kH];   // 64 KiB
  int tid = threadIdx.x;
  int t = blockIdx.x, jb = blockIdx.y;
  for (int i = tid; i < kB * kH / 4; i += 256) {
    int b = i >> 7;
    int tok = (t == 0) ? inputs[b] : tseq[b * kT + (t - 1)];
    ((f4*)Xs)[i] = ((const f4*)(emb + (size_t)tok * kH))[i & 127];
  }
  __syncthreads();
  int j2 = tid & 31, bq = tid >> 5;
  int j0 = jb * 64 + j2 * 2;
  int b0 = bq * 4;
  const f4* w0 = (const f4*)(Wih1 + (size_t)j0 * kH);
  const f4* w1 = (const f4*)(Wih1 + (size_t)(j0 + 1) * kH);
  float acc0[4] = {0.f, 0.f, 0.f, 0.f};
  float acc1[4] = {0.f, 0.f, 0.f, 0.f};
  #pragma unroll 2
  for (int k4 = 0; k4 < 128; ++k4) {
    f4 a0 = w0[k4], a1 = w1[k4];
    #pragma unroll
    for (int bb = 0; bb < 4; ++bb) {
      f4 x = ((const f4*)Xs)[(b0 + bb) * 128 + k4];
      acc0[bb] += a0.x * x.x + a0.y * x.y + a0.z * x.z + a0.w * x.w;
      acc1[bb] += a1.x * x.x + a1.y * x.y + a1.z * x.z + a1.w * x.w;
    }
  }
  float bj0 = bih1[j0] + bhh1[j0];
  float bj1 = bih1[j0 + 1] + bhh1[j0 + 1];
  f4 s0 = {acc0[0] + bj0, acc0[1] + bj0, acc0[2] + bj0, acc0[3] + bj0};
  f4 s1 = {acc1[0] + bj1, acc1[1] + bj1, acc1[2] + bj1, acc1[3] + bj1};
  float* o = Xg1T + ((size_t)t * kG + j0) * kB + b0;
  *(f4*)o = s0;
  *(f4*)(o + kB) = s1;
}

// ---------------------------------------------------------------------- K4
// Counter barrier, distributed over 8 lines (128 B apart). Producer:
// __syncthreads drains vmcnt(0) in every wave before thread 0 does one
// relaxed agent atomicAdd on line (w&7). Consumer: 8 lanes of wave 0 load
// the 8 lines, shuffle-sum, compare; then __syncthreads.
__device__ inline void postc(int* cnt) {
  __syncthreads();
  if (threadIdx.x == 0)
    __hip_atomic_fetch_add(&cnt[(blockIdx.x & 7) << 5], 1, __ATOMIC_RELAXED,
                           __HIP_MEMORY_SCOPE_AGENT);
}
__device__ inline void waitc(int* cnt, int target) {
  if (threadIdx.x < 64) {
    int lane = threadIdx.x;
    for (;;) {
      int v = (lane < 8)
                  ? __hip_atomic_load(&cnt[lane << 5], __ATOMIC_RELAXED,
                                      __HIP_MEMORY_SCOPE_AGENT)
                  : 0;
      v += __shfl_xor(v, 1);
      v += __shfl_xor(v, 2);
      v += __shfl_xor(v, 4);
      if (__shfl(v, 0) >= target) break;
      __builtin_amdgcn_s_sleep(2);
    }
  }
  __syncthreads();
}

// Stage 32x512 f32 h-state into LDS (f4 XOR-swizzle). Coherent variant uses
// relaxed agent u64 loads (bypasses stale L1 / non-coherent per-XCD L2).
__device__ inline void stage_coh(float* __restrict__ smem, const float* src) {
  const u64* s8 = (const u64*)src;
  #pragma unroll
  for (int i = 0; i < 16; ++i) {
    int idx = threadIdx.x + (i << 8);          // f4 index 0..4095
    u64 lo = __hip_atomic_load((u64*)&s8[idx * 2], __ATOMIC_RELAXED,
                               __HIP_MEMORY_SCOPE_AGENT);
    u64 hi = __hip_atomic_load((u64*)&s8[idx * 2 + 1], __ATOMIC_RELAXED,
                               __HIP_MEMORY_SCOPE_AGENT);
    int b_ = idx >> 7, k4 = idx & 127;
    union { u64 u[2]; f4 v; } cv; cv.u[0] = lo; cv.u[1] = hi;
    ((f4*)smem)[(b_ << 7) + (k4 ^ (b_ & 7))] = cv.v;
  }
}
__device__ inline void stage_plain(float* __restrict__ smem,
                                   const float* __restrict__ src) {
  const f4* s4 = (const f4*)src;
  #pragma unroll
  for (int i = 0; i < 16; ++i) {
    int idx = threadIdx.x + (i << 8);
    int b_ = idx >> 7, k4 = idx & 127;
    ((f4*)smem)[(b_ << 7) + (k4 ^ (b_ & 7))] = s4[idx];
  }
}

__device__ inline float redk(float s) {   // sum over 8 K-slice lanes
  s += __shfl_xor(s, 1);
  s += __shfl_xor(s, 2);
  s += __shfl_xor(s, 4);
  return s;
}

__global__ __launch_bounds__(256, 1) void k_serial(
    const float* __restrict__ hiddens, const float* __restrict__ Xg1T,
    const float* __restrict__ Whh1, const float* __restrict__ Wih2,
    const float* __restrict__ Whh2, const float* __restrict__ bih2,
    const float* __restrict__ bhh2,
    float* __restrict__ buf1, float* __restrict__ buf2,
    unsigned short* __restrict__ H2u,
    const unsigned short* __restrict__ Wu, const float* __restrict__ bout,
    float* __restrict__ outP, float* __restrict__ rs,
    float* __restrict__ outTail,
    int* __restrict__ cntA, int* __restrict__ cntB) {
  __shared__ float smemh[kB * kH];     // 64 KiB h-state stage
  __shared__ float wlds[24 * 4 * kWS]; // 48.4 KiB weights: rows m*8 + (2*gg+nl)
  __shared__ float sinv[4][32];        // per-wave softmax 1/rowsum scratch
  const int tid = threadIdx.x, w = blockIdx.x;
  const int lane = tid & 63, wv = tid >> 6;
  const int ks = lane & 7;             // K-slice 0..7, STRIDED: k4 = kk*8+ks
  const int nl = (lane >> 3) & 1;      // column select: n = 2w + nl
  const int bq = lane >> 4;            // 0..3
  const int bp = (wv << 2) | bq;       // b-pair 0..15
  const int b0 = bp << 1, b1 = b0 + 1;
  const int b0off = b0 << 7, b1off = b1 << 7;
  const int b0sw = b0 & 7, b1sw = b1 & 7;
  const int n = (w << 1) + nl;         // my hidden column
  // vocab-chunk geometry (valid for w < kNV)
  const int r16 = lane & 15, quad = lane >> 4;
  const int colb = w * 128 + wv * 32;
  float bo0 = 0.f, bo1 = 0.f;
  if (w < kNV) { bo0 = bout[colb + r16]; bo1 = bout[colb + 16 + r16]; }

  // ---- preload this WG's 24 weight rows into LDS (row = m*8 + jj,
  //      jj = 2*gg + nl; m=0:Whh1, 1:Whh2, 2:Wih2), stride kWS f4 ----
  {
    f4* wl = (f4*)wlds;
    #pragma unroll
    for (int i = 0; i < 12; ++i) {
      int idx = tid + (i << 8);                // 0..3071
      int row = idx >> 7, k4 = idx & 127;
      int m = row >> 3, jjr = row & 7;
      int jr = ((jjr >> 1) << 9) + (w << 1) + (jjr & 1);
      const float* src = (m == 0) ? Whh1 : (m == 1) ? Whh2 : Wih2;
      wl[row * kWS + k4] = ((const f4*)(src + (size_t)jr * kH))[k4];
    }
  }
  const f4* wr_hh1[4];
  const f4* wr_hh2[4];
  const f4* wr_ih2[4];
  #pragma unroll
  for (int gg = 0; gg < 4; ++gg) {
    int row = 2 * gg + nl;
    wr_hh1[gg] = (const f4*)wlds + (0 * 8 + row) * kWS;
    wr_hh2[gg] = (const f4*)wlds + (1 * 8 + row) * kWS;
    wr_ih2[gg] = (const f4*)wlds + (2 * 8 + row) * kWS;
  }
  float bj[4];
  #pragma unroll
  for (int gg = 0; gg < 4; ++gg)
    bj[gg] = bih2[(gg << 9) + n] + bhh2[(gg << 9) + n];

  const f4* hsm = (const f4*)smemh;
  float c1a = 0.f, c1b = 0.f, c2a = 0.f, c2b = 0.f;
  const f4 z4 = {0.f, 0.f, 0.f, 0.f};
  f4 p00 = z4, p01 = z4, p10 = z4, p11 = z4;   // exp'd probs, step t-1

  // vocab(tt): 32 rows (step tt) x my 32 cols; A=H2u[tt] (coh), B=Wu (plain)
  auto vocab_tile = [&](int tt) {
    p00 = z4; p01 = z4; p10 = z4; p11 = z4;
    const unsigned short* A0 = H2u + ((size_t)tt * kB + r16) * kH;
    const unsigned short* A1 = A0 + (size_t)16 * kH;
    const unsigned short* B0 = Wu + (size_t)(colb + r16) * kH;
    const unsigned short* B1 = B0 + (size_t)16 * kH;
    #pragma unroll 2
    for (int kb = 0; kb < 16; ++kb) {
      int k0 = kb * 32 + quad * 8;
      union { u64 u[2]; short8 s; } a0, a1;
      a0.u[0] = __hip_atomic_load((const u64*)(A0 + k0), __ATOMIC_RELAXED,
                                  __HIP_MEMORY_SCOPE_AGENT);
      a0.u[1] = __hip_atomic_load((const u64*)(A0 + k0 + 4), __ATOMIC_RELAXED,
                                  __HIP_MEMORY_SCOPE_AGENT);
      a1.u[0] = __hip_atomic_load((const u64*)(A1 + k0), __ATOMIC_RELAXED,
                                  __HIP_MEMORY_SCOPE_AGENT);
      a1.u[1] = __hip_atomic_load((const u64*)(A1 + k0 + 4), __ATOMIC_RELAXED,
                                  __HIP_MEMORY_SCOPE_AGENT);
      short8 vb0 = *(const short8*)(B0 + k0);
      short8 vb1 = *(const short8*)(B1 + k0);
      p00 = __builtin_amdgcn_mfma_f32_16x16x32_bf16(a0.s, vb0, p00, 0, 0, 0);
      p01 = __builtin_amdgcn_mfma_f32_16x16x32_bf16(a0.s, vb1, p01, 0, 0, 0);
      p10 = __builtin_amdgcn_mfma_f32_16x16x32_bf16(a1.s, vb0, p10, 0, 0, 0);
      p11 = __builtin_amdgcn_mfma_f32_16x16x32_bf16(a1.s, vb1, p11, 0, 0, 0);
    }
    float* rsb = rs + tt * 1024 + (w & 31) * 32;   // [slot][32 rows]
    #pragma unroll
    for (int r = 0; r < 4; ++r) {
      float e0 = __expf(p00[r] + bo0), e1 = __expf(p01[r] + bo1);
      p00[r] = e0; p01[r] = e1;
      float s = e0 + e1;
      s += __shfl_xor(s, 1); s += __shfl_xor(s, 2);
      s += __shfl_xor(s, 4); s += __shfl_xor(s, 8);
      if (r16 == 0) atomicAdd(&rsb[quad * 4 + r], s);
      float f0 = __expf(p10[r] + bo0), f1 = __expf(p11[r] + bo1);
      p10[r] = f0; p11[r] = f1;
      float u = f0 + f1;
      u += __shfl_xor(u, 1); u += __shfl_xor(u, 2);
      u += __shfl_xor(u, 4); u += __shfl_xor(u, 8);
      if (r16 == 0) atomicAdd(&rsb[16 + quad * 4 + r], u);
    }
  };
  // scale+store probs(ts): rowsums over 32 slots -> per-wave sinv -> stores
  auto scale_store = [&](int ts) {
    const float* rb = rs + ts * 1024;
    if (lane < 32) {
      float s = 0.f;
      #pragma unroll 8
      for (int sl = 0; sl < 32; ++sl) {
        union { unsigned u; float f; } cv;
        cv.u = __hip_atomic_load((const unsigned*)(rb + sl * 32 + lane),
                                 __ATOMIC_RELAXED, __HIP_MEMORY_SCOPE_AGENT);
        s += cv.f;
      }
      sinv[wv][lane] = 1.0f / s;
    }
    __syncthreads();
    float* ob = outP + (size_t)ts * kB * kV + colb;
    #pragma unroll
    for (int r = 0; r < 4; ++r) {
      {
        int rr = quad * 4 + r;
        float inv = sinv[wv][rr];
        float* orow = ob + (size_t)rr * kV;
        orow[r16] = p00[r] * inv;
        orow[16 + r16] = p01[r] * inv;
      }
      {
        int rr = 16 + quad * 4 + r;
        float inv = sinv[wv][rr];
        float* orow = ob + (size_t)rr * kV;
        orow[r16] = p10[r] * inv;
        orow[16 + r16] = p11[r] * inv;
      }
    }
  };

  stage_plain(smemh, hiddens);      // h1[-1]
  __syncthreads();
  for (int t = 0; t < kT; ++t) {
    float* h1w = buf1 + (t & 1) * 16384;
    float* h2w = buf2 + (t & 1) * 16384;
    const float* h2r = buf2 + ((t + 1) & 1) * 16384;   // h2[t-1]

    // prefetch x-gate terms (incl. layer-1 biases) for my (n, b0/b1)
    union { u64 u; float f[2]; } xv[4];
    const float* xbase = Xg1T + ((size_t)t * kG + n) * kB + b0;
    #pragma unroll
    for (int gg = 0; gg < 4; ++gg)
      xv[gg].u = *(const u64*)(xbase + (size_t)(gg << 9) * kB);

    // ---- layer-1: Whh1 . h1[t-1] over my strided K-slice, 4 gates x 2 b ----
    f4 a00 = z4, a01 = z4, a10 = z4, a11 = z4, a20 = z4, a21 = z4,
       a30 = z4, a31 = z4;
    #pragma unroll 4
    for (int kk = 0; kk < 16; ++kk) {
      int k4 = (kk << 3) | ks;
      f4 h0v = hsm[b0off + (k4 ^ b0sw)];
      f4 h1v = hsm[b1off + (k4 ^ b1sw)];
      f4 w0 = wr_hh1[0][k4], w1 = wr_hh1[1][k4];
      f4 w2 = wr_hh1[2][k4], w3 = wr_hh1[3][k4];
      a00 += w0 * h0v; a01 += w0 * h1v;
      a10 += w1 * h0v; a11 += w1 * h1v;
      a20 += w2 * h0v; a21 += w2 * h1v;
      a30 += w3 * h0v; a31 += w3 * h1v;
    }
    float G00 = redk(a00.x + a00.y + a00.z + a00.w) + xv[0].f[0];
    float G01 = redk(a01.x + a01.y + a01.z + a01.w) + xv[0].f[1];
    float G10 = redk(a10.x + a10.y + a10.z + a10.w) + xv[1].f[0];
    float G11 = redk(a11.x + a11.y + a11.z + a11.w) + xv[1].f[1];
    float G20 = redk(a20.x + a20.y + a20.z + a20.w) + xv[2].f[0];
    float G21 = redk(a21.x + a21.y + a21.z + a21.w) + xv[2].f[1];
    float G30 = redk(a30.x + a30.y + a30.z + a30.w) + xv[3].f[0];
    float G31 = redk(a31.x + a31.y + a31.z + a31.w) + xv[3].f[1];
    c1a = sigm(G10) * c1a + sigm(G00) * tanhf(G20);
    float hn0 = sigm(G30) * tanhf(c1a);
    c1b = sigm(G11) * c1b + sigm(G01) * tanhf(G21);
    float hn1 = sigm(G31) * tanhf(c1b);
    float hp0 = __shfl(hn0, lane ^ 8);   // partner column's h, same b
    float hp1 = __shfl(hn1, lane ^ 8);
    if ((lane & 15) == 0) {              // nl==0 && ks==0
      union { float f[2]; u64 u; } q0, q1;
      q0.f[0] = hn0; q0.f[1] = hp0;
      q1.f[0] = hn1; q1.f[1] = hp1;
      __hip_atomic_store((u64*)(h1w + b0 * kH + 2 * w), q0.u, __ATOMIC_RELAXED,
                         __HIP_MEMORY_SCOPE_AGENT);
      __hip_atomic_store((u64*)(h1w + b1 * kH + 2 * w), q1.u, __ATOMIC_RELAXED,
                         __HIP_MEMORY_SCOPE_AGENT);
      if (t == kT - 1) {
        *(u64*)(outTail + b0 * kH + 2 * w) = q0.u;     // final h1 output
        *(u64*)(outTail + b1 * kH + 2 * w) = q1.u;
      }
    }
    postc(cntA);                    // publish h1[t]
    waitc(cntB, 256 * t);           // h2[t-1] + H2u[t-1] + rs[t-2] final

    if (t >= 2 && w < kNV) scale_store(t - 2);   // consumes p** regs

    stage_coh(smemh, h2r);          // h2[t-1]
    __syncthreads();

    if (t >= 1 && w < kNV) vocab_tile(t - 1);    // produces p** regs

    // ---- layer-2 partial: Whh2 . h2[t-1] (overlaps other WGs' A-posts) ----
    a00 = z4; a01 = z4; a10 = z4; a11 = z4;
    a20 = z4; a21 = z4; a30 = z4; a31 = z4;
    #pragma unroll 4
    for (int kk = 0; kk < 16; ++kk) {
      int k4 = (kk << 3) | ks;
      f4 h0v = hsm[b0off + (k4 ^ b0sw)];
      f4 h1v = hsm[b1off + (k4 ^ b1sw)];
      f4 w0 = wr_hh2[0][k4], w1 = wr_hh2[1][k4];
      f4 w2 = wr_hh2[2][k4], w3 = wr_hh2[3][k4];
      a00 += w0 * h0v; a01 += w0 * h1v;
      a10 += w1 * h0v; a11 += w1 * h1v;
      a20 += w2 * h0v; a21 += w2 * h1v;
      a30 += w3 * h0v; a31 += w3 * h1v;
    }
    waitc(cntA, 256 * (t + 1));     // h1[t] visible from all WGs

    stage_coh(smemh, h1w);          // h1[t] (stays staged for next layer-1)
    __syncthreads();
    #pragma unroll 4
    for (int kk = 0; kk < 16; ++kk) {
      int k4 = (kk << 3) | ks;
      f4 h0v = hsm[b0off + (k4 ^ b0sw)];
      f4 h1v = hsm[b1off + (k4 ^ b1sw)];
      f4 w0 = wr_ih2[0][k4], w1 = wr_ih2[1][k4];
      f4 w2 = wr_ih2[2][k4], w3 = wr_ih2[3][k4];
      a00 += w0 * h0v; a01 += w0 * h1v;
      a10 += w1 * h0v; a11 += w1 * h1v;
      a20 += w2 * h0v; a21 += w2 * h1v;
      a30 += w3 * h0v; a31 += w3 * h1v;
    }
    G00 = redk(a00.x + a00.y + a00.z + a00.w) + bj[0];
    G01 = redk(a01.x + a01.y + a01.z + a01.w) + bj[0];
    G10 = redk(a10.x + a10.y + a10.z + a10.w) + bj[1];
    G11 = redk(a11.x + a11.y + a11.z + a11.w) + bj[1];
    G20 = redk(a20.x + a20.y + a20.z + a20.w) + bj[2];
    G21 = redk(a21.x + a21.y + a21.z + a21.w) + bj[2];
    G30 = redk(a30.x + a30.y + a30.z + a30.w) + bj[3];
    G31 = redk(a31.x + a31.y + a31.z + a31.w) + bj[3];
    c2a = sigm(G10) * c2a + sigm(G00) * tanhf(G20);
    float h2n0 = sigm(G30) * tanhf(c2a);
    c2b = sigm(G11) * c2b + sigm(G01) * tanhf(G21);
    float h2n1 = sigm(G31) * tanhf(c2b);
    float h2p0 = __shfl(h2n0, lane ^ 8);
    float h2p1 = __shfl(h2n1, lane ^ 8);
    if ((lane & 15) == 0) {              // nl==0 && ks==0
      union { float f[2]; u64 u; } q0, q1;
      q0.f[0] = h2n0; q0.f[1] = h2p0;
      q1.f[0] = h2n1; q1.f[1] = h2p1;
      __hip_atomic_store((u64*)(h2w + b0 * kH + 2 * w), q0.u, __ATOMIC_RELAXED,
                         __HIP_MEMORY_SCOPE_AGENT);
      __hip_atomic_store((u64*)(h2w + b1 * kH + 2 * w), q1.u, __ATOMIC_RELAXED,
                         __HIP_MEMORY_SCOPE_AGENT);
      unsigned bf0 = ((unsigned)f2bf(h2p0) << 16) | f2bf(h2n0);
      unsigned bf1 = ((unsigned)f2bf(h2p1) << 16) | f2bf(h2n1);
      __hip_atomic_store((unsigned*)(H2u + ((size_t)t * kB + b0) * kH + 2 * w),
                         bf0, __ATOMIC_RELAXED, __HIP_MEMORY_SCOPE_AGENT);
      __hip_atomic_store((unsigned*)(H2u + ((size_t)t * kB + b1) * kH + 2 * w),
                         bf1, __ATOMIC_RELAXED, __HIP_MEMORY_SCOPE_AGENT);
    }
    postc(cntB);                    // publish h2[t] (+ my vocab(t-1) rowsums)
    // smemh still holds h1[t] -> next iteration's layer-1 needs no restage
  }

  // ---- epilogue: drain the 2-deep softmax pipeline ----
  waitc(cntB, 256 * kT);            // h2[63]/H2u[63] + rs[62] final
  if (w < kNV) scale_store(kT - 2);
  if (w < kNV) vocab_tile(kT - 1);
  postc(cntA);                      // count -> 256*(kT+1), atomics drained
  waitc(cntA, 256 * (kT + 1));      // rs[63] final
  if (w < kNV) scale_store(kT - 1);
}

// ---------------------------------------------------------------------------
extern "C" void kernel_launch(void* const* d_in, const int* in_sizes, int n_in,
                              void* d_out, int out_size, void* d_ws, size_t ws_size,
                              hipStream_t stream) {
  (void)in_sizes; (void)n_in; (void)out_size; (void)ws_size;
  const int*   inputs  = (const int*)d_in[0];
  const float* hiddens = (const float*)d_in[1];
  const int*   tseq    = (const int*)d_in[2];
  const float* emb  = (const float*)d_in[4];
  const float* Wih1 = (const float*)d_in[5];
  const float* Whh1 = (const float*)d_in[6];
  const float* bih1 = (const float*)d_in[7];
  const float* bhh1 = (const float*)d_in[8];
  const float* Wih2 = (const float*)d_in[9];
  const float* Whh2 = (const float*)d_in[10];
  const float* bih2 = (const float*)d_in[11];
  const float* bhh2 = (const float*)d_in[12];
  const float* Wout = (const float*)d_in[13];
  const float* bout = (const float*)d_in[14];

  // workspace layout (float offsets); ~50 MiB
  float* ws = (float*)d_ws;
  float* Xg1T = ws;                                        //  4,194,304 f
  float* buf1 = ws + 4194304;                              //  2 x 16384 f
  float* buf2 = ws + 4227072;                              //  2 x 16384 f
  unsigned short* H2u = (unsigned short*)(ws + 4259840);   //  1,048,576 bf16
  unsigned short* Wu  = (unsigned short*)(ws + 4784128);   // 16,384,000 bf16
  float* rs = ws + 12976128;                               //  64*1024 f slots
  int* flags = (int*)(ws + 13041664);                      //  512 ints
  int* cntA = flags;                                       //  8 lines x 128 B
  int* cntB = flags + 256;                                 //  8 lines x 128 B

  float* out = (float*)d_out;
  float* outTail = out + (size_t)kT * kB * kV;             // final h1 (32x512)

  hipLaunchKernelGGL(k_init, dim3(64), dim3(256), 0, stream, buf2, rs, flags);
  hipLaunchKernelGGL(k_wcvt, dim3(1024), dim3(256), 0, stream, Wout, Wu);
  hipLaunchKernelGGL(k_xg1, dim3(64, 32), dim3(256), 0, stream,
                     inputs, tseq, emb, Wih1, bih1, bhh1, Xg1T);
  hipLaunchKernelGGL(k_serial, dim3(kNWG), dim3(256), 0, stream,
                     hiddens, Xg1T, Whh1, Wih2, Whh2, bih2, bhh2,
                     buf1, buf2, H2u, Wu, bout, out, rs, outTail, cntA, cntB);
}